// Round 1
// baseline (2041.862 us; speedup 1.0000x reference)
//
#include <hip/hip_runtime.h>
#include <hip/hip_bf16.h>
#include <stdint.h>

// Problem constants
#define NROWS 8192
#define FDIM 256
#define MCOLS 20000
#define NTILES 1250        // 20000 / 16, exact -> no tail masking
#define MSPLIT 16
#define NCLS 1000

// ws layout (bytes), total ~15.5 MB:
//   Mb   bf16 memory          : [0, 10240000)
//   Fb   bf16 box*5           : [10240000, 14434304)
//   wsel weighted sel logits  : [14434304, 14467072)
//   pm   partial max [16][N]  : [14467072, 14991360)
//   ps   partial sum [16][N]  : [14991360, 15515648)
//   bpart block partials      : [15515648, 15515776)

typedef short short8 __attribute__((ext_vector_type(8)));
typedef float f32x4 __attribute__((ext_vector_type(4)));

__device__ __forceinline__ unsigned short f2bf(float x) {
    unsigned u = __float_as_uint(x);
    unsigned r = (u + 0x7FFFu + ((u >> 16) & 1u)) >> 16;   // RNE
    return (unsigned short)r;
}

__global__ void conv_kernel(const float* __restrict__ in, unsigned short* __restrict__ out,
                            int n4, float scale) {
    int idx = blockIdx.x * blockDim.x + threadIdx.x;
    if (idx >= n4) return;
    float4 v = ((const float4*)in)[idx];
    ushort4 o;
    o.x = f2bf(v.x * scale); o.y = f2bf(v.y * scale);
    o.z = f2bf(v.z * scale); o.w = f2bf(v.w * scale);
    ((ushort4*)out)[idx] = o;
}

// Selected logits: wsel[i] = 5 * sum_d d * dot(F[i], Mem[trace[label_i][d]]), fp32-exact.
__global__ void sel_kernel(const int* __restrict__ gt, const float* __restrict__ F,
                           const float* __restrict__ Mem, const int* __restrict__ trace,
                           float* __restrict__ wsel) {
    int lane = threadIdx.x & 63, wid = threadIdx.x >> 6;
    int i = blockIdx.x * 4 + wid;
    int label = gt[i];
    float w = 0.0f;
    if (label >= 0 && label < NCLS) {
        float4 fv = ((const float4*)(F + (size_t)i * FDIM))[lane];
        #pragma unroll
        for (int d = 1; d <= 3; ++d) {
            int tr = trace[label * 4 + d];
            float4 mv = ((const float4*)(Mem + (size_t)tr * FDIM))[lane];
            float dot = fv.x*mv.x + fv.y*mv.y + fv.z*mv.z + fv.w*mv.w;
            #pragma unroll
            for (int off = 32; off >= 1; off >>= 1) dot += __shfl_xor(dot, off, 64);
            w += (float)d * dot;
        }
    }
    if (lane == 0) wsel[i] = w * 5.0f;   // 1/T
}

// Fused GEMM + online logsumexp partials.
// Block: 4 waves x 64 rows = 256 rows. A in registers; B tile (16 cols x 256 k)
// double-buffered in LDS with XOR swizzle (row&7)<<4 on 16B granules.
__global__ __launch_bounds__(256, 2) void lse_gemm(
        const unsigned short* __restrict__ Fb, const unsigned short* __restrict__ Mb,
        float* __restrict__ pm, float* __restrict__ ps) {
    __shared__ __align__(16) unsigned short smem[2 * 16 * FDIM];  // 16 KiB

    const int split  = blockIdx.x;   // 0..15  (== XCD id mod 8 for L2 locality)
    const int rowblk = blockIdx.y;   // 0..31
    const int tid  = threadIdx.x;
    const int lane = tid & 63, wid = tid >> 6;
    const int r0 = lane & 15, hi = lane >> 4;
    const int rowbase = rowblk * 256 + wid * 64;

    // A fragments: lane holds row (rowbase + rf*16 + r0), k = kk*32 + hi*8 .. +8
    short8 a[4][8];
    #pragma unroll
    for (int rf = 0; rf < 4; ++rf)
        #pragma unroll
        for (int kk = 0; kk < 8; ++kk)
            a[rf][kk] = *(const short8*)(Fb + (size_t)(rowbase + rf*16 + r0) * FDIM + kk*32 + hi*8);

    float m[16], s[16];
    #pragma unroll
    for (int q = 0; q < 16; ++q) { m[q] = -3.0e38f; s[q] = 0.0f; }

    const int t0 = (split * NTILES) / MSPLIT;
    const int t1 = ((split + 1) * NTILES) / MSPLIT;

    // staging: 512 granules of 16B per tile; this thread stages two.
    const int g0 = wid * 128 + lane;
    const int g1 = g0 + 64;
    const int j0 = g0 >> 5, o0 = g0 & 31;
    const int j1 = g1 >> 5, o1 = g1 & 31;
    const int sk0 = (o0 * 16) ^ ((j0 & 7) << 4);   // swizzled source byte within row
    const int sk1 = (o1 * 16) ^ ((j1 & 7) << 4);
    const int d0 = j0 * 512 + o0 * 16;             // linear LDS dest byte
    const int d1 = j1 * 512 + o1 * 16;

    {   // prologue: stage tile t0 into buffer 0
        const char* src = (const char*)(Mb + (size_t)t0 * 16 * FDIM);
        short8 v0 = *(const short8*)(src + j0 * 512 + sk0);
        short8 v1 = *(const short8*)(src + j1 * 512 + sk1);
        *(short8*)((char*)smem + d0) = v0;
        *(short8*)((char*)smem + d1) = v1;
    }
    __syncthreads();

    const int swzr = (r0 & 7) << 4;
    for (int t = t0; t < t1; ++t) {
        const int cur = (t - t0) & 1;
        short8 v0, v1;
        const bool hasNext = (t + 1 < t1);
        if (hasNext) {   // issue next-tile loads early; hide under MFMA
            const char* src = (const char*)(Mb + (size_t)(t + 1) * 16 * FDIM);
            v0 = *(const short8*)(src + j0 * 512 + sk0);
            v1 = *(const short8*)(src + j1 * 512 + sk1);
        }

        const char* bb = (const char*)smem + cur * 8192 + r0 * 512;
        f32x4 acc[4];
        #pragma unroll
        for (int rf = 0; rf < 4; ++rf) { f32x4 z = {0.f, 0.f, 0.f, 0.f}; acc[rf] = z; }
        #pragma unroll
        for (int kk = 0; kk < 8; ++kk) {
            const int K0 = kk * 64 + hi * 16;
            short8 b = *(const short8*)(bb + (K0 ^ swzr));
            #pragma unroll
            for (int rf = 0; rf < 4; ++rf)
                acc[rf] = __builtin_amdgcn_mfma_f32_16x16x32_bf16(a[rf][kk], b, acc[rf], 0, 0, 0);
        }

        // lane-local online softmax: this lane owns column (t*16 + r0), 16 rows.
        #pragma unroll
        for (int rf = 0; rf < 4; ++rf)
            #pragma unroll
            for (int r = 0; r < 4; ++r) {
                const int q = rf * 4 + r;
                float v = acc[rf][r];
                if (v <= m[q]) {
                    s[q] += __expf(v - m[q]);
                } else {
                    s[q] = s[q] * __expf(m[q] - v) + 1.0f;
                    m[q] = v;
                }
            }

        __syncthreads();
        if (hasNext) {
            char* wb = (char*)smem + (cur ^ 1) * 8192;
            *(short8*)(wb + d0) = v0;
            *(short8*)(wb + d1) = v1;
        }
        __syncthreads();
    }

    // combine the 16 lanes of each quarter-wave group (per-lane column subsets)
    #pragma unroll
    for (int off = 1; off <= 8; off <<= 1) {
        #pragma unroll
        for (int q = 0; q < 16; ++q) {
            float om = __shfl_xor(m[q], off, 64);
            float os = __shfl_xor(s[q], off, 64);
            float nm = fmaxf(m[q], om);
            float sn = s[q] * __expf(m[q] - nm) + os * __expf(om - nm);
            m[q] = nm; s[q] = sn;
        }
    }
    if (r0 == 0) {
        #pragma unroll
        for (int rf = 0; rf < 4; ++rf)
            #pragma unroll
            for (int r = 0; r < 4; ++r) {
                int row = rowbase + rf * 16 + hi * 4 + r;   // C/D: row=(lane>>4)*4+reg
                pm[split * NROWS + row] = m[rf * 4 + r];
                ps[split * NROWS + row] = s[rf * 4 + r];
            }
    }
}

__global__ void finalize_kernel(const int* __restrict__ gt, const float* __restrict__ wsel,
                                const float* __restrict__ pm, const float* __restrict__ ps,
                                float* __restrict__ bpart) {
    int tid = threadIdx.x;
    int i = blockIdx.x * 256 + tid;
    float mv[MSPLIT];
    float M = -3.0e38f;
    #pragma unroll
    for (int k = 0; k < MSPLIT; ++k) { mv[k] = pm[k * NROWS + i]; M = fmaxf(M, mv[k]); }
    float S = 0.0f;
    #pragma unroll
    for (int k = 0; k < MSPLIT; ++k) S += ps[k * NROWS + i] * __expf(mv[k] - M);
    float lse = M + __logf(S);
    int label = gt[i];
    float per = (label >= 0 && label < NCLS) ? (lse - wsel[i] * (1.0f / 6.0f)) : 0.0f;
    #pragma unroll
    for (int off = 32; off >= 1; off >>= 1) per += __shfl_xor(per, off, 64);
    __shared__ float red[4];
    int lane = tid & 63, wid = tid >> 6;
    if (lane == 0) red[wid] = per;
    __syncthreads();
    if (tid == 0) bpart[blockIdx.x] = red[0] + red[1] + red[2] + red[3];
}

__global__ void sum_kernel(const float* __restrict__ bpart, float* __restrict__ out) {
    int tid = threadIdx.x;
    float v = (tid < 32) ? bpart[tid] : 0.0f;
    #pragma unroll
    for (int off = 32; off >= 1; off >>= 1) v += __shfl_xor(v, off, 64);
    if (tid == 0) out[0] = 0.001f * v;
}

extern "C" void kernel_launch(void* const* d_in, const int* in_sizes, int n_in,
                              void* d_out, int out_size, void* d_ws, size_t ws_size,
                              hipStream_t stream) {
    const int*   gt    = (const int*)d_in[0];
    const float* F     = (const float*)d_in[1];
    const float* Mem   = (const float*)d_in[2];
    const int*   trace = (const int*)d_in[3];
    float* out = (float*)d_out;

    char* w = (char*)d_ws;
    unsigned short* Mb = (unsigned short*)w;
    unsigned short* Fb = (unsigned short*)(w + 10240000);
    float* wsel  = (float*)(w + 14434304);
    float* pm    = (float*)(w + 14467072);
    float* ps    = (float*)(w + 14991360);
    float* bpart = (float*)(w + 15515648);

    conv_kernel<<<dim3((MCOLS * FDIM / 4) / 256), dim3(256), 0, stream>>>(Mem, Mb, MCOLS * FDIM / 4, 1.0f);
    conv_kernel<<<dim3((NROWS * FDIM / 4) / 256), dim3(256), 0, stream>>>(F, Fb, NROWS * FDIM / 4, 5.0f);
    sel_kernel<<<dim3(NROWS / 4), dim3(256), 0, stream>>>(gt, F, Mem, trace, wsel);
    lse_gemm<<<dim3(MSPLIT, NROWS / 256), dim3(256), 0, stream>>>(Fb, Mb, pm, ps);
    finalize_kernel<<<dim3(NROWS / 256), dim3(256), 0, stream>>>(gt, wsel, pm, ps, bpart);
    sum_kernel<<<dim3(1), dim3(64), 0, stream>>>(bpart, out);
}

// Round 2
// 245.402 us; speedup vs baseline: 8.3205x; 8.3205x over previous
//
#include <hip/hip_runtime.h>
#include <hip/hip_bf16.h>
#include <stdint.h>

// Problem constants
#define NROWS 8192
#define FDIM 256
#define MCOLS 20000
#define NTILES 1250        // 20000 / 16, exact -> no tail masking
#define MSPLIT 16
#define NCLS 1000

// ws layout (bytes), total ~15.5 MB:
//   Mb   bf16 memory          : [0, 10240000)
//   Fb   bf16 box*5           : [10240000, 14434304)
//   wsel weighted sel logits  : [14434304, 14467072)
//   pm   partial max [16][N]  : [14467072, 14991360)
//   ps   partial sum [16][N]  : [14991360, 15515648)
//   bpart block partials      : [15515648, 15515776)

typedef short short8 __attribute__((ext_vector_type(8)));
typedef float f32x4 __attribute__((ext_vector_type(4)));

typedef __attribute__((address_space(3))) unsigned int lds_u32;
typedef const __attribute__((address_space(1))) unsigned int glb_u32;

__device__ __forceinline__ unsigned short f2bf(float x) {
    unsigned u = __float_as_uint(x);
    unsigned r = (u + 0x7FFFu + ((u >> 16) & 1u)) >> 16;   // RNE
    return (unsigned short)r;
}

__global__ void conv_kernel(const float* __restrict__ in, unsigned short* __restrict__ out,
                            int n4, float scale) {
    int idx = blockIdx.x * blockDim.x + threadIdx.x;
    if (idx >= n4) return;
    float4 v = ((const float4*)in)[idx];
    ushort4 o;
    o.x = f2bf(v.x * scale); o.y = f2bf(v.y * scale);
    o.z = f2bf(v.z * scale); o.w = f2bf(v.w * scale);
    ((ushort4*)out)[idx] = o;
}

// Selected logits: wsel[i] = 5 * sum_d d * dot(F[i], Mem[trace[label_i][d]]), fp32-exact.
__global__ void sel_kernel(const int* __restrict__ gt, const float* __restrict__ F,
                           const float* __restrict__ Mem, const int* __restrict__ trace,
                           float* __restrict__ wsel) {
    int lane = threadIdx.x & 63, wid = threadIdx.x >> 6;
    int i = blockIdx.x * 4 + wid;
    int label = gt[i];
    float w = 0.0f;
    if (label >= 0 && label < NCLS) {
        float4 fv = ((const float4*)(F + (size_t)i * FDIM))[lane];
        #pragma unroll
        for (int d = 1; d <= 3; ++d) {
            int tr = trace[label * 4 + d];
            float4 mv = ((const float4*)(Mem + (size_t)tr * FDIM))[lane];
            float dot = fv.x*mv.x + fv.y*mv.y + fv.z*mv.z + fv.w*mv.w;
            #pragma unroll
            for (int off = 32; off >= 1; off >>= 1) dot += __shfl_xor(dot, off, 64);
            w += (float)d * dot;
        }
    }
    if (lane == 0) wsel[i] = w * 5.0f;   // 1/T
}

// Fused GEMM + online logsumexp partials.
// Block: 4 waves x 32 rows = 128 rows. A in registers (a[2][8] = 64 VGPRs);
// B tile (16 cols x 256 k) double-buffered in LDS via global_load_lds (linear
// dest, XOR-swizzled per-lane GLOBAL source -> conflict-free swizzled reads).
__global__ __launch_bounds__(256, 2) void lse_gemm(
        const unsigned short* __restrict__ Fb, const unsigned short* __restrict__ Mb,
        float* __restrict__ pm, float* __restrict__ ps) {
    __shared__ __align__(16) unsigned short smem[2 * 16 * FDIM];  // 16 KiB

    const int split  = blockIdx.x;   // 0..15 ; blockid%8 == split%8 -> XCD-local B chunk
    const int rowblk = blockIdx.y;   // 0..63
    const int tid  = threadIdx.x;
    const int lane = tid & 63, wid = tid >> 6;
    const int r0 = lane & 15, hi = lane >> 4;
    const int rowbase = rowblk * 128 + wid * 32;

    // A fragments: lane holds row (rowbase + rf*16 + r0), k = kk*32 + hi*8 .. +8
    short8 a[2][8];
    #pragma unroll
    for (int rf = 0; rf < 2; ++rf)
        #pragma unroll
        for (int kk = 0; kk < 8; ++kk)
            a[rf][kk] = *(const short8*)(Fb + (size_t)(rowbase + rf*16 + r0) * FDIM + kk*32 + hi*8);

    float m[8], s[8];
    #pragma unroll
    for (int q = 0; q < 8; ++q) { m[q] = -3.0e38f; s[q] = 0.0f; }

    const int t0 = (split * NTILES) / MSPLIT;
    const int t1 = ((split + 1) * NTILES) / MSPLIT;

    // Staging: tile = 512 granules of 16B. Wave w stages granules [w*128, w*128+128)
    // via 2 global_load_lds calls (64 lanes x 16B each). LDS dest is LINEAR
    // (granule g at byte g*16); source is pre-swizzled: LDS row j, slot o holds
    // source granule o^(j&7) so the read-side XOR lands on linear data.
    int srcoff[2];
    #pragma unroll
    for (int c = 0; c < 2; ++c) {
        const int g = (wid * 2 + c) * 64 + lane;
        const int j = g >> 5, o = g & 31;
        srcoff[c] = j * 512 + ((o ^ (j & 7)) << 4);   // byte offset within tile
    }

#define STAGE(buf, t)                                                              \
    {                                                                              \
        const char* srcT = (const char*)Mb + (size_t)(t) * (16 * FDIM * 2);        \
        _Pragma("unroll")                                                          \
        for (int c = 0; c < 2; ++c) {                                              \
            __builtin_amdgcn_global_load_lds(                                      \
                (glb_u32*)(srcT + srcoff[c]),                                      \
                (lds_u32*)((char*)smem + (buf) * 8192 + (wid * 2 + c) * 1024),     \
                16, 0, 0);                                                         \
        }                                                                          \
    }

    STAGE(0, t0);
    __syncthreads();   // drains vmcnt(0) -> tile t0 resident

    const int swzr = (r0 & 7) << 4;
    for (int t = t0; t < t1; ++t) {
        const int cur = (t - t0) & 1;
        if (t + 1 < t1) STAGE(cur ^ 1, t + 1);   // async prefetch under compute

        const char* bb = (const char*)smem + cur * 8192 + r0 * 512;
        f32x4 acc[2];
        #pragma unroll
        for (int rf = 0; rf < 2; ++rf) { f32x4 z = {0.f, 0.f, 0.f, 0.f}; acc[rf] = z; }
        #pragma unroll
        for (int kk = 0; kk < 8; ++kk) {
            short8 b = *(const short8*)(bb + ((kk * 64 + hi * 16) ^ swzr));
            acc[0] = __builtin_amdgcn_mfma_f32_16x16x32_bf16(a[0][kk], b, acc[0], 0, 0, 0);
            acc[1] = __builtin_amdgcn_mfma_f32_16x16x32_bf16(a[1][kk], b, acc[1], 0, 0, 0);
        }

        // lane-local online softmax: this lane owns column (t*16 + r0), 8 rows.
        #pragma unroll
        for (int rf = 0; rf < 2; ++rf)
            #pragma unroll
            for (int r = 0; r < 4; ++r) {
                const int q = rf * 4 + r;
                float v = acc[rf][r];
                if (v <= m[q]) {
                    s[q] += __expf(v - m[q]);
                } else {
                    s[q] = s[q] * __expf(m[q] - v) + 1.0f;
                    m[q] = v;
                }
            }

        __syncthreads();   // vmcnt(0): next tile resident; all waves done with cur
    }
#undef STAGE

    // combine the 16 lanes (r0 = column residue classes) of each hi-group
    #pragma unroll
    for (int off = 1; off <= 8; off <<= 1) {
        #pragma unroll
        for (int q = 0; q < 8; ++q) {
            float om = __shfl_xor(m[q], off, 64);
            float os = __shfl_xor(s[q], off, 64);
            float nm = fmaxf(m[q], om);
            float sn = s[q] * __expf(m[q] - nm) + os * __expf(om - nm);
            m[q] = nm; s[q] = sn;
        }
    }
    if (r0 == 0) {
        #pragma unroll
        for (int rf = 0; rf < 2; ++rf)
            #pragma unroll
            for (int r = 0; r < 4; ++r) {
                int row = rowbase + rf * 16 + hi * 4 + r;   // C/D: row=(lane>>4)*4+reg
                pm[split * NROWS + row] = m[rf * 4 + r];
                ps[split * NROWS + row] = s[rf * 4 + r];
            }
    }
}

__global__ void finalize_kernel(const int* __restrict__ gt, const float* __restrict__ wsel,
                                const float* __restrict__ pm, const float* __restrict__ ps,
                                float* __restrict__ bpart) {
    int tid = threadIdx.x;
    int i = blockIdx.x * 256 + tid;
    float mv[MSPLIT];
    float M = -3.0e38f;
    #pragma unroll
    for (int k = 0; k < MSPLIT; ++k) { mv[k] = pm[k * NROWS + i]; M = fmaxf(M, mv[k]); }
    float S = 0.0f;
    #pragma unroll
    for (int k = 0; k < MSPLIT; ++k) S += ps[k * NROWS + i] * __expf(mv[k] - M);
    float lse = M + __logf(S);
    int label = gt[i];
    float per = (label >= 0 && label < NCLS) ? (lse - wsel[i] * (1.0f / 6.0f)) : 0.0f;
    #pragma unroll
    for (int off = 32; off >= 1; off >>= 1) per += __shfl_xor(per, off, 64);
    __shared__ float red[4];
    int lane = tid & 63, wid = tid >> 6;
    if (lane == 0) red[wid] = per;
    __syncthreads();
    if (tid == 0) bpart[blockIdx.x] = red[0] + red[1] + red[2] + red[3];
}

__global__ void sum_kernel(const float* __restrict__ bpart, float* __restrict__ out) {
    int tid = threadIdx.x;
    float v = (tid < 32) ? bpart[tid] : 0.0f;
    #pragma unroll
    for (int off = 32; off >= 1; off >>= 1) v += __shfl_xor(v, off, 64);
    if (tid == 0) out[0] = 0.001f * v;
}

extern "C" void kernel_launch(void* const* d_in, const int* in_sizes, int n_in,
                              void* d_out, int out_size, void* d_ws, size_t ws_size,
                              hipStream_t stream) {
    const int*   gt    = (const int*)d_in[0];
    const float* F     = (const float*)d_in[1];
    const float* Mem   = (const float*)d_in[2];
    const int*   trace = (const int*)d_in[3];
    float* out = (float*)d_out;

    char* w = (char*)d_ws;
    unsigned short* Mb = (unsigned short*)w;
    unsigned short* Fb = (unsigned short*)(w + 10240000);
    float* wsel  = (float*)(w + 14434304);
    float* pm    = (float*)(w + 14467072);
    float* ps    = (float*)(w + 14991360);
    float* bpart = (float*)(w + 15515648);

    conv_kernel<<<dim3((MCOLS * FDIM / 4) / 256), dim3(256), 0, stream>>>(Mem, Mb, MCOLS * FDIM / 4, 1.0f);
    conv_kernel<<<dim3((NROWS * FDIM / 4) / 256), dim3(256), 0, stream>>>(F, Fb, NROWS * FDIM / 4, 5.0f);
    sel_kernel<<<dim3(NROWS / 4), dim3(256), 0, stream>>>(gt, F, Mem, trace, wsel);
    lse_gemm<<<dim3(MSPLIT, NROWS / 128), dim3(256), 0, stream>>>(Fb, Mb, pm, ps);
    finalize_kernel<<<dim3(NROWS / 256), dim3(256), 0, stream>>>(gt, wsel, pm, ps, bpart);
    sum_kernel<<<dim3(1), dim3(64), 0, stream>>>(bpart, out);
}

// Round 3
// 112.952 us; speedup vs baseline: 18.0773x; 2.1726x over previous
//
#include <hip/hip_runtime.h>
#include <hip/hip_bf16.h>
#include <stdint.h>

// Problem constants
#define NROWS 8192
#define FDIM 256
#define MCOLS 20000
#define NT32 625           // 20000 / 32, exact -> no tail masking
#define MSPLIT 16
#define NCLS 1000
#define LOG2E 1.44269504088896f
#define LN2   0.69314718055994f

// ws layout (bytes), total ~15.5 MB:
//   Mb   bf16 memory          : [0, 10240000)
//   Fb   bf16 box*5*log2e     : [10240000, 14434304)
//   wsel weighted sel logits  : [14434304, 14467072)
//   pm   partial max [16][N]  : [14467072, 14991360)
//   ps   partial sum [16][N]  : [14991360, 15515648)
//   bpart block partials      : [15515648, 15515776)

typedef short short8 __attribute__((ext_vector_type(8)));
typedef float f32x4 __attribute__((ext_vector_type(4)));

typedef __attribute__((address_space(3))) unsigned int lds_u32;
typedef const __attribute__((address_space(1))) unsigned int glb_u32;

__device__ __forceinline__ float ex2(float x) {   // raw v_exp_f32 (2^x), no ocml wrapper
    float r;
    asm("v_exp_f32 %0, %1" : "=v"(r) : "v"(x));
    return r;
}

__device__ __forceinline__ unsigned short f2bf(float x) {
    unsigned u = __float_as_uint(x);
    unsigned r = (u + 0x7FFFu + ((u >> 16) & 1u)) >> 16;   // RNE
    return (unsigned short)r;
}

__global__ void conv_kernel(const float* __restrict__ in, unsigned short* __restrict__ out,
                            int n4, float scale) {
    int idx = blockIdx.x * blockDim.x + threadIdx.x;
    if (idx >= n4) return;
    float4 v = ((const float4*)in)[idx];
    ushort4 o;
    o.x = f2bf(v.x * scale); o.y = f2bf(v.y * scale);
    o.z = f2bf(v.z * scale); o.w = f2bf(v.w * scale);
    ((ushort4*)out)[idx] = o;
}

// Selected logits: wsel[i] = 5 * sum_d d * dot(F[i], Mem[trace[label_i][d]]), fp32-exact,
// natural-log domain (independent of the exp2 trick in lse_gemm).
__global__ void sel_kernel(const int* __restrict__ gt, const float* __restrict__ F,
                           const float* __restrict__ Mem, const int* __restrict__ trace,
                           float* __restrict__ wsel) {
    int lane = threadIdx.x & 63, wid = threadIdx.x >> 6;
    int i = blockIdx.x * 4 + wid;
    int label = gt[i];
    float w = 0.0f;
    if (label >= 0 && label < NCLS) {
        float4 fv = ((const float4*)(F + (size_t)i * FDIM))[lane];
        #pragma unroll
        for (int d = 1; d <= 3; ++d) {
            int tr = trace[label * 4 + d];
            float4 mv = ((const float4*)(Mem + (size_t)tr * FDIM))[lane];
            float dot = fv.x*mv.x + fv.y*mv.y + fv.z*mv.z + fv.w*mv.w;
            #pragma unroll
            for (int off = 32; off >= 1; off >>= 1) dot += __shfl_xor(dot, off, 64);
            w += (float)d * dot;
        }
    }
    if (lane == 0) wsel[i] = w * 5.0f;   // 1/T
}

// Fused GEMM + online log2-sum-exp2 partials.
// Block: 4 waves x 32 rows = 128 rows. A in registers (a[2][8] = 64 VGPRs);
// B tile (32 cols x 256 k, 16 KiB) double-buffered in LDS via global_load_lds
// (linear dest, XOR-swizzled per-lane GLOBAL source -> conflict-free reads).
__global__ __launch_bounds__(256, 2) void lse_gemm(
        const unsigned short* __restrict__ Fb, const unsigned short* __restrict__ Mb,
        float* __restrict__ pm, float* __restrict__ ps) {
    __shared__ __align__(16) char smem[2 * 16384];  // 32 KiB

    const int split  = blockIdx.x;   // 0..15 ; consecutive x -> different XCDs
    const int rowblk = blockIdx.y;   // 0..63
    const int tid  = threadIdx.x;
    const int lane = tid & 63, wid = tid >> 6;
    const int r0 = lane & 15, hi = lane >> 4;
    const int rowbase = rowblk * 128 + wid * 32;

    // A fragments: lane holds row (rowbase + rf*16 + r0), k = kk*32 + hi*8 .. +8
    short8 a[2][8];
    #pragma unroll
    for (int rf = 0; rf < 2; ++rf)
        #pragma unroll
        for (int kk = 0; kk < 8; ++kk)
            a[rf][kk] = *(const short8*)(Fb + (size_t)(rowbase + rf*16 + r0) * FDIM + kk*32 + hi*8);

    float m[8], s[8];
    #pragma unroll
    for (int q = 0; q < 8; ++q) { m[q] = -3.0e38f; s[q] = 0.0f; }

    const int t0 = (split * NT32) / MSPLIT;
    const int t1 = ((split + 1) * NT32) / MSPLIT;

    // Staging: tile = 1024 granules of 16B (32 rows x 512B). Each thread stages 4
    // granules. LDS dest LINEAR; global source pre-swizzled (o ^ (j&7)) so the
    // read-side XOR hits linear data.
    int srcoff[4];
    #pragma unroll
    for (int c = 0; c < 4; ++c) {
        const int g = (wid * 4 + c) * 64 + lane;
        const int j = g >> 5, o = g & 31;
        srcoff[c] = j * 512 + ((o ^ (j & 7)) << 4);
    }

#define STAGE(buf, t)                                                              \
    do {                                                                           \
        const char* srcT = (const char*)Mb + (size_t)(t) * 16384;                  \
        _Pragma("unroll")                                                          \
        for (int c = 0; c < 4; ++c) {                                              \
            __builtin_amdgcn_global_load_lds(                                      \
                (glb_u32*)(srcT + srcoff[c]),                                      \
                (lds_u32*)((char*)smem + (buf) * 16384 + (wid * 4 + c) * 1024),    \
                16, 0, 0);                                                         \
        }                                                                          \
    } while (0)

    // Hoisted swizzled read offsets (per kk), buf/col-half become imm offsets.
    const int swzr = (r0 & 7) << 4;
    int roff[8];
    #pragma unroll
    for (int kk = 0; kk < 8; ++kk)
        roff[kk] = r0 * 512 + ((kk * 64 + hi * 16) ^ swzr);

#define BODY(BUF, t, pref)                                                         \
    do {                                                                           \
        if (pref) STAGE((BUF) ^ 1, (t) + 1);                                       \
        f32x4 acc00 = {0,0,0,0}, acc01 = {0,0,0,0}, acc10 = {0,0,0,0}, acc11 = {0,0,0,0}; \
        _Pragma("unroll")                                                          \
        for (int kk = 0; kk < 8; ++kk) {                                           \
            short8 b0 = *(const short8*)(smem + roff[kk] + (BUF) * 16384);         \
            short8 b1 = *(const short8*)(smem + roff[kk] + (BUF) * 16384 + 8192);  \
            acc00 = __builtin_amdgcn_mfma_f32_16x16x32_bf16(a[0][kk], b0, acc00, 0, 0, 0); \
            acc10 = __builtin_amdgcn_mfma_f32_16x16x32_bf16(a[1][kk], b0, acc10, 0, 0, 0); \
            acc01 = __builtin_amdgcn_mfma_f32_16x16x32_bf16(a[0][kk], b1, acc01, 0, 0, 0); \
            acc11 = __builtin_amdgcn_mfma_f32_16x16x32_bf16(a[1][kk], b1, acc11, 0, 0, 0); \
        }                                                                          \
        _Pragma("unroll")                                                          \
        for (int r = 0; r < 4; ++r) {                                              \
            { float v0 = acc00[r], v1 = acc01[r];                                  \
              float nm = fmaxf(fmaxf(m[r], v0), v1);                               \
              float em = ex2(m[r] - nm), e0 = ex2(v0 - nm), e1 = ex2(v1 - nm);     \
              s[r] = fmaf(s[r], em, e0 + e1); m[r] = nm; }                         \
            { float v0 = acc10[r], v1 = acc11[r];                                  \
              float nm = fmaxf(fmaxf(m[4 + r], v0), v1);                           \
              float em = ex2(m[4 + r] - nm), e0 = ex2(v0 - nm), e1 = ex2(v1 - nm); \
              s[4 + r] = fmaf(s[4 + r], em, e0 + e1); m[4 + r] = nm; }             \
        }                                                                          \
        __syncthreads();                                                           \
    } while (0)

    STAGE(0, t0);
    __syncthreads();

    int t = t0;
    while (t + 2 <= t1) {
        BODY(0, t, true);
        BODY(1, t + 1, (t + 2 < t1));
        t += 2;
    }
    if (t < t1) BODY(0, t, false);   // odd-count tail: tile already resident in buf 0

#undef BODY
#undef STAGE

    // combine the 16 lanes (r0 = column residue classes) of each hi-group
    #pragma unroll
    for (int off = 1; off <= 8; off <<= 1) {
        #pragma unroll
        for (int q = 0; q < 8; ++q) {
            float om = __shfl_xor(m[q], off, 64);
            float os = __shfl_xor(s[q], off, 64);
            float nm = fmaxf(m[q], om);
            float sn = fmaf(s[q], ex2(m[q] - nm), os * ex2(om - nm));
            m[q] = nm; s[q] = sn;
        }
    }
    if (r0 == 0) {
        #pragma unroll
        for (int rf = 0; rf < 2; ++rf)
            #pragma unroll
            for (int r = 0; r < 4; ++r) {
                int row = rowbase + rf * 16 + hi * 4 + r;   // C/D: row=(lane>>4)*4+reg
                pm[split * NROWS + row] = m[rf * 4 + r];
                ps[split * NROWS + row] = s[rf * 4 + r];
            }
    }
}

__global__ void finalize_kernel(const int* __restrict__ gt, const float* __restrict__ wsel,
                                const float* __restrict__ pm, const float* __restrict__ ps,
                                float* __restrict__ bpart) {
    int tid = threadIdx.x;
    int i = blockIdx.x * 256 + tid;
    float mv[MSPLIT];
    float M = -3.0e38f;
    #pragma unroll
    for (int k = 0; k < MSPLIT; ++k) { mv[k] = pm[k * NROWS + i]; M = fmaxf(M, mv[k]); }
    float S = 0.0f;
    #pragma unroll
    for (int k = 0; k < MSPLIT; ++k) S += ps[k * NROWS + i] * ex2(mv[k] - M);
    float lse = (M + __log2f(S)) * LN2;   // back to natural-log domain
    int label = gt[i];
    float per = (label >= 0 && label < NCLS) ? (lse - wsel[i] * (1.0f / 6.0f)) : 0.0f;
    #pragma unroll
    for (int off = 32; off >= 1; off >>= 1) per += __shfl_xor(per, off, 64);
    __shared__ float red[4];
    int lane = tid & 63, wid = tid >> 6;
    if (lane == 0) red[wid] = per;
    __syncthreads();
    if (tid == 0) bpart[blockIdx.x] = red[0] + red[1] + red[2] + red[3];
}

__global__ void sum_kernel(const float* __restrict__ bpart, float* __restrict__ out) {
    int tid = threadIdx.x;
    float v = (tid < 32) ? bpart[tid] : 0.0f;
    #pragma unroll
    for (int off = 32; off >= 1; off >>= 1) v += __shfl_xor(v, off, 64);
    if (tid == 0) out[0] = 0.001f * v;
}

extern "C" void kernel_launch(void* const* d_in, const int* in_sizes, int n_in,
                              void* d_out, int out_size, void* d_ws, size_t ws_size,
                              hipStream_t stream) {
    const int*   gt    = (const int*)d_in[0];
    const float* F     = (const float*)d_in[1];
    const float* Mem   = (const float*)d_in[2];
    const int*   trace = (const int*)d_in[3];
    float* out = (float*)d_out;

    char* w = (char*)d_ws;
    unsigned short* Mb = (unsigned short*)w;
    unsigned short* Fb = (unsigned short*)(w + 10240000);
    float* wsel  = (float*)(w + 14434304);
    float* pm    = (float*)(w + 14467072);
    float* ps    = (float*)(w + 14991360);
    float* bpart = (float*)(w + 15515648);

    conv_kernel<<<dim3((MCOLS * FDIM / 4) / 256), dim3(256), 0, stream>>>(Mem, Mb, MCOLS * FDIM / 4, 1.0f);
    conv_kernel<<<dim3((NROWS * FDIM / 4) / 256), dim3(256), 0, stream>>>(F, Fb, NROWS * FDIM / 4, 5.0f * LOG2E);
    sel_kernel<<<dim3(NROWS / 4), dim3(256), 0, stream>>>(gt, F, Mem, trace, wsel);
    lse_gemm<<<dim3(MSPLIT, NROWS / 128), dim3(256), 0, stream>>>(Fb, Mb, pm, ps);
    finalize_kernel<<<dim3(NROWS / 256), dim3(256), 0, stream>>>(gt, wsel, pm, ps, bpart);
    sum_kernel<<<dim3(1), dim3(64), 0, stream>>>(bpart, out);
}